// Round 5
// baseline (423.469 us; speedup 1.0000x reference)
//
#include <hip/hip_runtime.h>

// GCN layer: out = segment_sum(edge_weight * (X@W)[edge_src], edge_dst) + bias
// Round 5: (a) GEMM BM64/BN128/BK64, DOUBLE-buffered LDS staging via
//              global_load_lds(16B) + XOR swizzle; 2 blocks/CU.
//          (b) agg: 64 lanes per dst row (1 row/wave, no divergence waste),
//              wave-uniform csr reads, unroll x4.
// ws layout (bytes):
//   hbf       [M*128 bf16]   @ 0          (25.6 MB)
//   Wt bf16   [128*512]      @ 25,600,000 (0.13 MB)  Wt[n][k]
//   deg  int  [M]            @ 25,731,072
//   rs   int  [M+1]          @ 26,131,072
//   cur  int  [M]            @ 26,531,088
//   csr  u64  [E]            @ 26,931,088 (5.12 MB)  (w_bits<<32 | src)
//   bsum int  [128]          @ 32,051,088

#define D_IN  512
#define D_OUT 128

typedef __attribute__((ext_vector_type(8))) short short8;
typedef __attribute__((ext_vector_type(4))) float f32x4;
typedef __attribute__((ext_vector_type(4))) int i32x4;

typedef __attribute__((address_space(1))) const unsigned int glob_u32;
typedef __attribute__((address_space(3))) unsigned int lds_u32;

static __device__ __forceinline__ unsigned short f2bf(float f) {
    unsigned u = __float_as_uint(f);
    unsigned r = (u + 0x7FFFu + ((u >> 16) & 1u)) >> 16;   // RNE
    return (unsigned short)r;
}

// pack two fp32 -> two bf16 (truncation; v_perm)
static __device__ __forceinline__ int pack2(float lo, float hi) {
    return (int)((__float_as_uint(hi) & 0xFFFF0000u) | (__float_as_uint(lo) >> 16));
}

// ---- prep: Wt[n][k] = bf16(W[k][n]);  deg = 0 ----
__global__ __launch_bounds__(256) void prep_kernel(const float* __restrict__ W,
                                                   unsigned short* __restrict__ Wt,
                                                   int* __restrict__ deg, int M) {
    int t = blockIdx.x * 256 + threadIdx.x;
    if (t < D_OUT * D_IN) {
        int n = t >> 9;
        int k = t & 511;
        Wt[t] = f2bf(W[(size_t)k * D_OUT + n]);
    }
    if (t < M) deg[t] = 0;
}

// ---- GEMM: hbf[M,128] = bf16(X[M,512] @ W), MFMA 16x16x32 bf16 ----
// Block: 256 thr / 4 waves (2x2), tile 64 rows x 128 cols, BK=64.
// Double-buffered: A fp32 16KB + B bf16 16KB per buffer, 64KB total LDS.
// Stage chunk c+1 before computing chunk c; one barrier per chunk.
__global__ __launch_bounds__(256, 2) void gemm_kernel(const float* __restrict__ X,
                                                      const unsigned short* __restrict__ Wt,
                                                      unsigned short* __restrict__ H, int M) {
    __shared__ float As[2][64 * 64];            // slot s (16B) = row*16 + (kq ^ (row&15))
    __shared__ unsigned short Bs[2][128 * 64];  // slot s (16B) = n*8 + (kq8 ^ (n&7))

    const int tid = threadIdx.x;
    const int lane = tid & 63;
    const int w = tid >> 6;
    const int block_row = blockIdx.x * 64;

    const int m = lane & 15;
    const int q = lane >> 4;
    const int wave_row = (w >> 1) * 32;   // 2 row-tiles of 16
    const int wave_col = (w & 1) * 64;    // 4 col-tiles of 16

    f32x4 acc[2][4];
#pragma unroll
    for (int a = 0; a < 2; a++)
#pragma unroll
        for (int b = 0; b < 4; b++) acc[a][b] = (f32x4){0.f, 0.f, 0.f, 0.f};

    // ---- staging helper (manually inlined twice below) ----
    // A: 1024 slots of 16B (64 rows x 16 kq), 4 instrs/wave
    // B: 1024 slots of 16B (128 n x 8 kq8),   4 instrs/wave
#define STAGE_CHUNK(KC, BUF)                                                          \
    {                                                                                 \
        _Pragma("unroll")                                                             \
        for (int it = 0; it < 4; it++) {                                              \
            int slot_base = w * 256 + it * 64;                                        \
            int s = slot_base + lane;                                                 \
            int row = s >> 4;                                                         \
            int kq = (s & 15) ^ (row & 15);                                           \
            int grow = block_row + row;                                               \
            if (grow >= M) grow = M - 1;                                              \
            const float* gp = X + (size_t)grow * D_IN + (KC) + kq * 4;                \
            __builtin_amdgcn_global_load_lds((glob_u32*)gp,                           \
                (lds_u32*)(&As[BUF][0] + (size_t)slot_base * 4), 16, 0, 0);           \
        }                                                                             \
        _Pragma("unroll")                                                             \
        for (int it = 0; it < 4; it++) {                                              \
            int slot_base = w * 256 + it * 64;                                        \
            int s = slot_base + lane;                                                 \
            int n = s >> 3;                                                           \
            int kq8 = (s & 7) ^ (n & 7);                                              \
            const unsigned short* gp = Wt + (size_t)n * D_IN + (KC) + kq8 * 8;        \
            __builtin_amdgcn_global_load_lds((glob_u32*)gp,                           \
                (lds_u32*)(&Bs[BUF][0] + (size_t)slot_base * 8), 16, 0, 0);           \
        }                                                                             \
    }

    STAGE_CHUNK(0, 0);
    __syncthreads();

#pragma unroll
    for (int c = 0; c < 8; c++) {
        const int cur = c & 1;
        if (c < 7) STAGE_CHUNK((c + 1) * 64, cur ^ 1);

        // ---- compute chunk c from buffer cur: 2 ksubs x 8 MFMAs ----
#pragma unroll
        for (int ks = 0; ks < 2; ks++) {
            const int ksub = ks * 32;
            short8 afr[2];
#pragma unroll
            for (int rg = 0; rg < 2; rg++) {
                int row = wave_row + rg * 16 + m;
                int kq0 = (ksub >> 2) + 2 * q;
                float4 u0 = *reinterpret_cast<const float4*>(
                    &As[cur][0] + (size_t)(row * 16 + (kq0 ^ (row & 15))) * 4);
                float4 u1 = *reinterpret_cast<const float4*>(
                    &As[cur][0] + (size_t)(row * 16 + ((kq0 + 1) ^ (row & 15))) * 4);
                i32x4 ai;
                ai.x = pack2(u0.x, u0.y);
                ai.y = pack2(u0.z, u0.w);
                ai.z = pack2(u1.x, u1.y);
                ai.w = pack2(u1.z, u1.w);
                afr[rg] = __builtin_bit_cast(short8, ai);
            }
            short8 bfr[4];
#pragma unroll
            for (int cg = 0; cg < 4; cg++) {
                int n = wave_col + cg * 16 + m;
                int kq8 = (ksub >> 3) + q;
                bfr[cg] = *reinterpret_cast<const short8*>(
                    &Bs[cur][0] + (size_t)(n * 8 + (kq8 ^ (n & 7))) * 8);
            }
#pragma unroll
            for (int rg = 0; rg < 2; rg++)
#pragma unroll
                for (int cg = 0; cg < 4; cg++)
                    acc[rg][cg] = __builtin_amdgcn_mfma_f32_16x16x32_bf16(
                        afr[rg], bfr[cg], acc[rg][cg], 0, 0, 0);
        }
        __syncthreads();
    }

    // ---- epilogue: C layout col = m, row = q*4 + r ----
#pragma unroll
    for (int rg = 0; rg < 2; rg++) {
#pragma unroll
        for (int r = 0; r < 4; r++) {
            int grow = block_row + wave_row + rg * 16 + q * 4 + r;
            if (grow < M) {
#pragma unroll
                for (int cg = 0; cg < 4; cg++)
                    H[(size_t)grow * D_OUT + wave_col + cg * 16 + m] = f2bf(acc[rg][cg][r]);
            }
        }
    }
#undef STAGE_CHUNK
}

// ---- histogram of dst ----
__global__ __launch_bounds__(256) void hist_kernel(const int* __restrict__ dst,
                                                   int* __restrict__ deg, int E) {
    int e = blockIdx.x * 256 + threadIdx.x;
    if (e < E) atomicAdd(&deg[dst[e]], 1);
}

// ---- scan pass 1: per-1024-chunk local exclusive scan + chunk totals ----
__global__ __launch_bounds__(256) void scan1_kernel(const int* __restrict__ deg,
                                                    int* __restrict__ rs,
                                                    int* __restrict__ bsum, int M) {
    __shared__ int sdata[256];
    const int tid = threadIdx.x;
    const int base = blockIdx.x * 1024 + tid * 4;
    int v[4];
#pragma unroll
    for (int i = 0; i < 4; i++) v[i] = (base + i < M) ? deg[base + i] : 0;
    int tsum = v[0] + v[1] + v[2] + v[3];
    sdata[tid] = tsum;
    __syncthreads();
    for (int off = 1; off < 256; off <<= 1) {
        int add = (tid >= off) ? sdata[tid - off] : 0;
        __syncthreads();
        sdata[tid] += add;
        __syncthreads();
    }
    int excl = sdata[tid] - tsum;
#pragma unroll
    for (int i = 0; i < 4; i++) {
        if (base + i < M) rs[base + i] = excl;
        excl += v[i];
    }
    if (tid == 255) bsum[blockIdx.x] = sdata[255];
}

// ---- scan pass 2: exclusive scan of chunk totals (<=128 chunks) ----
__global__ __launch_bounds__(128) void scan2_kernel(int* __restrict__ bsum, int NB) {
    __shared__ int sdata[128];
    const int tid = threadIdx.x;
    int v = (tid < NB) ? bsum[tid] : 0;
    sdata[tid] = v;
    __syncthreads();
    for (int off = 1; off < 128; off <<= 1) {
        int add = (tid >= off) ? sdata[tid - off] : 0;
        __syncthreads();
        sdata[tid] += add;
        __syncthreads();
    }
    if (tid < NB) bsum[tid] = sdata[tid] - v;
}

// ---- scan pass 3: apply chunk offsets; fill cursor; set rs[M]=E ----
__global__ __launch_bounds__(256) void scan3_kernel(int* __restrict__ rs,
                                                    int* __restrict__ cur,
                                                    const int* __restrict__ bsum,
                                                    int M, int E) {
    int i = blockIdx.x * 256 + threadIdx.x;
    if (i < M) {
        int val = rs[i] + bsum[i >> 10];
        rs[i] = val;
        cur[i] = val;
    }
    if (i == 0) rs[M] = E;
}

// ---- build CSR: csr[pos] = (w_bits<<32) | src ----
__global__ __launch_bounds__(256) void build_kernel(const int* __restrict__ src,
                                                    const int* __restrict__ dst,
                                                    const float* __restrict__ w,
                                                    int* __restrict__ cur,
                                                    unsigned long long* __restrict__ csr,
                                                    int E) {
    int e = blockIdx.x * 256 + threadIdx.x;
    if (e >= E) return;
    int d = dst[e];
    int pos = atomicAdd(&cur[d], 1);
    csr[pos] = ((unsigned long long)__float_as_uint(w[e]) << 32) | (unsigned)src[e];
}

// ---- aggregate: out[d] = bias + sum_{e in row d} w_e * h[src_e]  (no atomics) ----
// 64 lanes per dst row (1 row per wave -> zero inter-row divergence).
// Lane c owns cols {2c, 2c+1}: one u32 (2 bf16) gather per edge.
// csr/rs addresses are wave-uniform -> scalar loads. Unroll x4.
__global__ __launch_bounds__(256) void agg_kernel(const unsigned short* __restrict__ H,
                                                  const int* __restrict__ rs,
                                                  const unsigned long long* __restrict__ csr,
                                                  const float* __restrict__ bias,
                                                  float* __restrict__ out, int M) {
    int row = blockIdx.x * 4 + (threadIdx.x >> 6);
    if (row >= M) return;
    int c = threadIdx.x & 63;                       // col pair id

    float2 acc = *((const float2*)bias + c);
    int j = rs[row];
    int end = rs[row + 1];
    const unsigned int* Hc = (const unsigned int*)H + c;   // + s*64 per source row

    for (; j + 4 <= end; j += 4) {
        unsigned long long p0 = csr[j];
        unsigned long long p1 = csr[j + 1];
        unsigned long long p2 = csr[j + 2];
        unsigned long long p3 = csr[j + 3];
        unsigned v0 = Hc[(size_t)(unsigned)(p0 & 0xFFFFFFFFull) * 64];
        unsigned v1 = Hc[(size_t)(unsigned)(p1 & 0xFFFFFFFFull) * 64];
        unsigned v2 = Hc[(size_t)(unsigned)(p2 & 0xFFFFFFFFull) * 64];
        unsigned v3 = Hc[(size_t)(unsigned)(p3 & 0xFFFFFFFFull) * 64];
        float w0 = __uint_as_float((unsigned)(p0 >> 32));
        float w1 = __uint_as_float((unsigned)(p1 >> 32));
        float w2 = __uint_as_float((unsigned)(p2 >> 32));
        float w3 = __uint_as_float((unsigned)(p3 >> 32));
        acc.x += w0 * __uint_as_float(v0 << 16);
        acc.y += w0 * __uint_as_float(v0 & 0xFFFF0000u);
        acc.x += w1 * __uint_as_float(v1 << 16);
        acc.y += w1 * __uint_as_float(v1 & 0xFFFF0000u);
        acc.x += w2 * __uint_as_float(v2 << 16);
        acc.y += w2 * __uint_as_float(v2 & 0xFFFF0000u);
        acc.x += w3 * __uint_as_float(v3 << 16);
        acc.y += w3 * __uint_as_float(v3 & 0xFFFF0000u);
    }
    for (; j < end; j++) {
        unsigned long long p0 = csr[j];
        float w0 = __uint_as_float((unsigned)(p0 >> 32));
        unsigned v0 = Hc[(size_t)(unsigned)(p0 & 0xFFFFFFFFull) * 64];
        acc.x += w0 * __uint_as_float(v0 << 16);
        acc.y += w0 * __uint_as_float(v0 & 0xFFFF0000u);
    }

    *((float2*)(out + (size_t)row * D_OUT) + c) = acc;
}

extern "C" void kernel_launch(void* const* d_in, const int* in_sizes, int n_in,
                              void* d_out, int out_size, void* d_ws, size_t ws_size,
                              hipStream_t stream) {
    const float* features    = (const float*)d_in[0];
    const int*   edge_src    = (const int*)d_in[1];
    const int*   edge_dst    = (const int*)d_in[2];
    const float* edge_weight = (const float*)d_in[3];
    const float* weights     = (const float*)d_in[4];
    const float* bias        = (const float*)d_in[5];
    float* out = (float*)d_out;

    const int M = in_sizes[0] / D_IN;   // 100000
    const int E = in_sizes[1];          // 640000

    char* ws = (char*)d_ws;
    unsigned short* hbf = (unsigned short*)(ws);                       // M*128 bf16
    unsigned short* Wt  = (unsigned short*)(ws + 25600000);            // 128*512 bf16
    int* deg            = (int*)(ws + 25731072);                       // M
    int* rs             = (int*)(ws + 26131072);                       // M+1
    int* cur            = (int*)(ws + 26531088);                       // M
    unsigned long long* csr = (unsigned long long*)(ws + 26931088);    // E
    int* bsum           = (int*)(ws + 32051088);                       // 128

    // 1) Wt = bf16(W^T); deg = 0
    prep_kernel<<<(M + 255) / 256, 256, 0, stream>>>(weights, Wt, deg, M);
    // 2) hbf = bf16(X @ W)  (MFMA, double-buffered LDS)
    gemm_kernel<<<(M + 63) / 64, 256, 0, stream>>>(features, Wt, hbf, M);
    // 3) CSR build
    hist_kernel<<<(E + 255) / 256, 256, 0, stream>>>(edge_dst, deg, E);
    const int NB = (M + 1023) / 1024;   // 98 chunks
    scan1_kernel<<<NB, 256, 0, stream>>>(deg, rs, bsum, M);
    scan2_kernel<<<1, 128, 0, stream>>>(bsum, NB);
    scan3_kernel<<<(M + 255) / 256, 256, 0, stream>>>(rs, cur, bsum, M, E);
    build_kernel<<<(E + 255) / 256, 256, 0, stream>>>(edge_src, edge_dst, edge_weight,
                                                      cur, csr, E);
    // 4) gather-aggregate, bias fused, one store per output row
    agg_kernel<<<(M + 3) / 4, 256, 0, stream>>>(hbf, rs, csr, bias, out, M);
}